// Round 1
// baseline (523.265 us; speedup 1.0000x reference)
//
#include <hip/hip_runtime.h>
#include <cmath>

#define Hdim 512
#define Udim 32
#define Bdim 32
#define Tdim 2048
#define RM   64    // rows per block in K1 (lane == row)
#define KC   32    // k-chunk
#define LDX  36    // padded LDS row stride (floats)
#define NU   8     // u-columns per lane (one u-slice per wave)
#define CH   128   // delta rows per LDS chunk in K2

// ---------------- Kernel 1: gamma/beta GEMMs + tanh + lambd combine -> delta [B*T, U] ----------
// Wave-uniform u-slice => weight loads are scalar (s_load through K$), FMA reads weight from SGPR.
// Per q-iter per wave: 2 ds_read_b128 (acts) for 128 FMAs (was 12 b128 / 64 FMA => LDS-pipe-bound).
__global__ __launch_bounds__(256, 4) void k1_gemm_act(
    const float* __restrict__ x, const float* __restrict__ tin,
    const float* __restrict__ kx, const float* __restrict__ kt,
    const float* __restrict__ bx, const float* __restrict__ bt,
    const float* __restrict__ lambd, float* __restrict__ delta)
{
    __shared__ float xs[RM * LDX];
    __shared__ float ts[RM * LDX];

    const int tid  = threadIdx.x;
    const int lane = tid & 63;
    const int u0   = __builtin_amdgcn_readfirstlane((tid >> 6) * NU);  // wave-uniform u-slice
    const int row0 = blockIdx.x * RM;

    // staging: 64 rows x 8 float4 (KC=32 floats) per matrix; 256 threads -> 2 float4 each
    const int srow = tid >> 3;   // 0..31
    const int sf4  = tid & 7;    // 0..7

    const float4* xg = (const float4*)x;
    const float4* tg = (const float4*)tin;

    float4 px[2], pt[2];
    float accx[NU], acct[NU];
#pragma unroll
    for (int uu = 0; uu < NU; ++uu) { accx[uu] = 0.f; acct[uu] = 0.f; }

    // prefetch chunk 0
#pragma unroll
    for (int l = 0; l < 2; ++l) {
        const size_t r = (size_t)(row0 + srow + 32 * l);
        px[l] = xg[r * (Hdim / 4) + sf4];
        pt[l] = tg[r * (Hdim / 4) + sf4];
    }

#pragma unroll 1
    for (int c = 0; c < Hdim / KC; ++c) {
        __syncthreads();
#pragma unroll
        for (int l = 0; l < 2; ++l) {
            *(float4*)&xs[(srow + 32 * l) * LDX + sf4 * 4] = px[l];
            *(float4*)&ts[(srow + 32 * l) * LDX + sf4 * 4] = pt[l];
        }
        __syncthreads();

        if (c + 1 < Hdim / KC) {
#pragma unroll
            for (int l = 0; l < 2; ++l) {
                const size_t r = (size_t)(row0 + srow + 32 * l);
                px[l] = xg[r * (Hdim / 4) + (c + 1) * (KC / 4) + sf4];
                pt[l] = tg[r * (Hdim / 4) + (c + 1) * (KC / 4) + sf4];
            }
        }

#pragma unroll
        for (int q = 0; q < KC / 4; ++q) {
            // activations: lane's own row, 4 k at a time (balanced 8-phase LDS access, LDX=36)
            float4 av = *(const float4*)&xs[lane * LDX + 4 * q];
            float4 bv = *(const float4*)&ts[lane * LDX + 4 * q];
            float a4[4] = { av.x, av.y, av.z, av.w };
            float b4[4] = { bv.x, bv.y, bv.z, bv.w };
            // weights: fully uniform addresses -> s_load_dwordx8 per (kk, matrix)
            const float* wxp = kx + (size_t)(c * KC + 4 * q) * Udim + u0;
            const float* wtp = kt + (size_t)(c * KC + 4 * q) * Udim + u0;
#pragma unroll
            for (int kk = 0; kk < 4; ++kk)
#pragma unroll
                for (int uu = 0; uu < NU; ++uu) {
                    accx[uu] = fmaf(a4[kk], wxp[kk * Udim + uu], accx[uu]);
                    acct[uu] = fmaf(b4[kk], wtp[kk * Udim + uu], acct[uu]);
                }
        }
    }

    // epilogue: each lane owns (row, u0..u0+7)
    const int grow = row0 + lane;
    const float lam = lambd[grow & (Tdim - 1)];
    float o[NU];
#pragma unroll
    for (int uu = 0; uu < NU; ++uu) {
        float g  = tanhf(accx[uu] + bx[u0 + uu]);   // bias: uniform scalar loads
        float be = tanhf(acct[uu] + bt[u0 + uu]);
        o[uu] = lam * g + (1.0f - lam) * be;
    }
    float* dp = delta + (size_t)grow * Udim + u0;
    *(float4*)&dp[0] = make_float4(o[0], o[1], o[2], o[3]);
    *(float4*)&dp[4] = make_float4(o[4], o[5], o[6], o[7]);
}

// ---------------- Kernel 2: scores = delta @ kernel_a, softmax over T -> alpha -----------------
// grid: 256 blocks, blockIdx.x = ht*32 + b (XCD = b%8 -> same-b blocks share an XCD L2)
// block: 1024 threads = 16 waves; tx = h lane (64 h per block), ty = wave
// delta staged through LDS in 128-row double-buffered chunks; each wave handles rows t%16==ty.
__global__ __launch_bounds__(1024, 2) void k2_softmax(
    const float* __restrict__ delta, const float* __restrict__ ka_g,
    float* __restrict__ alpha)
{
    __shared__ float dsm[2][CH * Udim];   // 2 x 16 KB
    __shared__ float ms[16][64];
    __shared__ float ls[16][64];

    const int tid = threadIdx.x;
    const int tx  = tid & 63;
    const int ty  = tid >> 6;          // 0..15
    const int b   = blockIdx.x & 31;
    const int ht  = blockIdx.x >> 5;   // 0..7
    const int h   = ht * 64 + tx;

    // kernel_a column for this lane's h (32 VGPRs)
    float ka[Udim];
#pragma unroll
    for (int u = 0; u < Udim; ++u) ka[u] = ka_g[u * Hdim + h];

    const float4* dsrc = (const float4*)(delta + (size_t)b * Tdim * Udim);

    // ---- pass 1: online (m, l) ----
    ((float4*)dsm[0])[tid] = dsrc[tid];   // stage chunk 0 (1024 float4 = 128 rows)

    float m = -1e30f, l = 0.f;
#pragma unroll 1
    for (int c = 0; c < Tdim / CH; ++c) {
        __syncthreads();
        const float* cur = dsm[c & 1];
        if (c + 1 < Tdim / CH)
            ((float4*)dsm[(c + 1) & 1])[tid] = dsrc[(size_t)(c + 1) * (CH * Udim / 4) + tid];
#pragma unroll
        for (int i = 0; i < CH / 16; ++i) {
            const int r = ty + 16 * i;
            const float4* dp = (const float4*)(cur + r * Udim);
            float4 q[8];
#pragma unroll
            for (int j = 0; j < 8; ++j) q[j] = dp[j];
            float s0 = 0.f, s1 = 0.f, s2 = 0.f, s3 = 0.f;
#pragma unroll
            for (int j = 0; j < 8; ++j) {
                s0 = fmaf(q[j].x, ka[4 * j],     s0);
                s1 = fmaf(q[j].y, ka[4 * j + 1], s1);
                s2 = fmaf(q[j].z, ka[4 * j + 2], s2);
                s3 = fmaf(q[j].w, ka[4 * j + 3], s3);
            }
            const float s = (s0 + s1) + (s2 + s3);
            const float mn = fmaxf(m, s);
            l = l * __expf(m - mn) + __expf(s - mn);
            m = mn;
        }
    }

    ms[ty][tx] = m;
    ls[ty][tx] = l;
    __syncthreads();
    float M = -1e30f;
#pragma unroll
    for (int w = 0; w < 16; ++w) M = fmaxf(M, ms[w][tx]);
    float L = 0.f;
#pragma unroll
    for (int w = 0; w < 16; ++w) L += ls[w][tx] * __expf(ms[w][tx] - M);
    const float rinv = 1.0f / L;

    // ---- pass 2: recompute scores, write alpha ----
    ((float4*)dsm[0])[tid] = dsrc[tid];   // restage chunk 0 (dsm[0] idle since c=14 sync)

    float* abase = alpha + (size_t)b * Tdim * Hdim + h;
#pragma unroll 1
    for (int c = 0; c < Tdim / CH; ++c) {
        __syncthreads();
        const float* cur = dsm[c & 1];
        if (c + 1 < Tdim / CH)
            ((float4*)dsm[(c + 1) & 1])[tid] = dsrc[(size_t)(c + 1) * (CH * Udim / 4) + tid];
#pragma unroll
        for (int i = 0; i < CH / 16; ++i) {
            const int r = ty + 16 * i;
            const int t = c * CH + r;
            const float4* dp = (const float4*)(cur + r * Udim);
            float4 q[8];
#pragma unroll
            for (int j = 0; j < 8; ++j) q[j] = dp[j];
            float s0 = 0.f, s1 = 0.f, s2 = 0.f, s3 = 0.f;
#pragma unroll
            for (int j = 0; j < 8; ++j) {
                s0 = fmaf(q[j].x, ka[4 * j],     s0);
                s1 = fmaf(q[j].y, ka[4 * j + 1], s1);
                s2 = fmaf(q[j].z, ka[4 * j + 2], s2);
                s3 = fmaf(q[j].w, ka[4 * j + 3], s3);
            }
            const float s = (s0 + s1) + (s2 + s3);
            abase[(size_t)t * Hdim] = __expf(s - M) * rinv;
        }
    }
}

extern "C" void kernel_launch(void* const* d_in, const int* in_sizes, int n_in,
                              void* d_out, int out_size, void* d_ws, size_t ws_size,
                              hipStream_t stream) {
    const float* x     = (const float*)d_in[0];
    const float* tin   = (const float*)d_in[1];
    const float* kx    = (const float*)d_in[2];
    const float* kt    = (const float*)d_in[3];
    const float* ka    = (const float*)d_in[4];
    const float* bx    = (const float*)d_in[5];
    const float* bt    = (const float*)d_in[6];
    const float* lambd = (const float*)d_in[7];
    float* alpha = (float*)d_out;
    float* delta = (float*)d_ws;   // B*T*U*4 = 8 MB

    k1_gemm_act<<<(Bdim * Tdim) / RM, 256, 0, stream>>>(x, tin, kx, kt, bx, bt, lambd, delta);
    k2_softmax<<<256, 1024, 0, stream>>>(delta, ka, alpha);
}